// Round 9
// baseline (516.117 us; speedup 1.0000x reference)
//
#include <hip/hip_runtime.h>
#include <cstdint>
#include <cstddef>

// ---------------------------------------------------------------------------
// SSTAFormer round 11 (= round 10 resubmit; round-10 bench was an infra
// failure, source re-audited: no barrier divergence, no slot overflow, no
// double-buffer race, overlay discipline intact).
//   Double-buffered, issue-early/write-late weight staging:
//   - r9 evidence: staging worked (225 us, Mfma 12.9%) but ~60% idle = barrier
//     convoy: every stage exposes its global latency to all 4 waves.
//   - Now: WB[2][4352] slots; each phase prefetches next stage to REGISTERS
//     before computing from current slot, ds_writes after, ONE barrier/phase.
//     38 phases; stage latency hides under compute of the previous phase.
//   - Stage granularity: L1 16-col (3072 u16), L2/L3 32-col (4096), TCN/QKV
//     32-col halves (2048). LDS total unchanged 54272 B -> 3 wg/CU.
// ---------------------------------------------------------------------------

typedef __attribute__((ext_vector_type(8))) __bf16 bf16x8;
typedef __attribute__((ext_vector_type(4))) float  f32x4;

#define MFMA16(a,b,c) __builtin_amdgcn_mfma_f32_16x16x32_bf16((a),(b),(c),0,0,0)
#define FENCE() __threadfence_block()

#define NGR    16384
#define EDGES  1048576
#define PRED_ELEMS (16*16384*24)

// workspace layout in ushort units
#define O_W1L 0               // [128][192]
#define O_W1R 24576
#define O_W2L 49152           // [128][128]
#define O_W2R 65536
#define O_W3L 81920           // [64][128]
#define O_W3R 90112
#define O_T0  98304           // [64 co][64 ci]  (tcn_w[...,0])
#define O_T1  102400
#define O_WQ  106496          // [64][64]
#define O_WK  110592
#define O_WV  114688
#define O_WO  118784
#define O_FC1 122880          // 16 x [64][128]
#define O_FC2 253952          // 16 x [32][64]
#define O_FEAT 286720         // [16384][128] bf16
#define PREP_TOT 286720

static __device__ __forceinline__ unsigned short f2bf(float f){
  unsigned int u = __builtin_bit_cast(unsigned int, f);
  u += 0x7FFFu + ((u >> 16) & 1u);            // RNE
  return (unsigned short)(u >> 16);
}
static __device__ __forceinline__ float bf2f(unsigned short h){
  return __builtin_bit_cast(float, (unsigned int)h << 16);
}
static __device__ __forceinline__ bf16x8 ld8(const unsigned short* p){
  return __builtin_bit_cast(bf16x8, *(const uint4*)p);   // 16B aligned by construction
}
static __device__ __forceinline__ bf16x8 zero8(){
  uint4 u = make_uint4(0u,0u,0u,0u);
  return __builtin_bit_cast(bf16x8, u);
}
static __device__ __forceinline__ unsigned int pkbf2(float a, float b){
  return (unsigned int)f2bf(a) | ((unsigned int)f2bf(b)<<16);
}
static __device__ __forceinline__ bf16x8 u4bf(unsigned int a, unsigned int b,
                                              unsigned int c, unsigned int d){
  uint4 u = make_uint4(a,b,c,d);
  return __builtin_bit_cast(bf16x8, u);
}
// C-layout (row=4*quad'+r, col=l15) -> B-frag (k=8*quad+e, col=l15)
static __device__ __forceinline__ bf16x8 shfrag(unsigned int p0, unsigned int p1,
                                                int laneA, int laneB){
  return u4bf((unsigned int)__shfl((int)p0, laneA, 64),
              (unsigned int)__shfl((int)p1, laneA, 64),
              (unsigned int)__shfl((int)p0, laneB, 64),
              (unsigned int)__shfl((int)p1, laneB, 64));
}
// A-fragment from global fp32 x row (K padded 168->192, W rows >=168 are zero)
static __device__ __forceinline__ bf16x8 xfrag(const float* __restrict__ xrow, int k0){
  int ks = (k0 < 168) ? k0 : 0;          // clamped lanes multiply zero W rows
  float4 f0 = *(const float4*)(xrow + ks);
  float4 f1 = *(const float4*)(xrow + ks + 4);
  return u4bf(pkbf2(f0.x,f0.y), pkbf2(f0.z,f0.w),
              pkbf2(f1.x,f1.y), pkbf2(f1.z,f1.w));
}
// issue-early: load TOT ushorts into regs (1-2 uint4/thread, tail predicated)
template<int TOT>
static __device__ __forceinline__ void sload(const unsigned short* __restrict__ src,
                                             int tid, uint4* r){
  #pragma unroll
  for (int i=0;i<TOT/2048;++i)
    r[i] = *(const uint4*)(src + i*2048 + tid*8);
  if constexpr ((TOT & 2047) != 0){
    if (tid < (TOT & 2047)/8)
      r[TOT/2048] = *(const uint4*)(src + (TOT/2048)*2048 + tid*8);
  }
}
// write-late: regs -> padded LDS slot (row K -> stride P)
template<int TOT,int K,int P>
static __device__ __forceinline__ void sstore(unsigned short* __restrict__ dst,
                                              int tid, const uint4* r){
  #pragma unroll
  for (int i=0;i<TOT/2048;++i){
    int idx = i*2048 + tid*8, row = idx / K;
    *(uint4*)(dst + row*P + (idx - row*K)) = r[i];
  }
  if constexpr ((TOT & 2047) != 0){
    if (tid < (TOT & 2047)/8){
      int idx = (TOT/2048)*2048 + tid*8, row = idx / K;
      *(uint4*)(dst + row*P + (idx - row*K)) = r[TOT/2048];
    }
  }
}
#define PH_NEXT(TOT,K,P) do{ sstore<TOT,K,P>(WB[cur^1], tid, rg); __syncthreads(); cur^=1; }while(0)

// ---------------------------------------------------------------------------
// weight prep (unchanged, verified correct)
// ---------------------------------------------------------------------------
__global__ __launch_bounds__(256) void k_prep(
  const float* __restrict__ w1l, const float* __restrict__ w1r,
  const float* __restrict__ w2l, const float* __restrict__ w2r,
  const float* __restrict__ w3l, const float* __restrict__ w3r,
  const float* __restrict__ tcnw,
  const float* __restrict__ wq, const float* __restrict__ wk,
  const float* __restrict__ wv, const float* __restrict__ wo,
  const float* __restrict__ fc1w, const float* __restrict__ fc2w,
  unsigned short* __restrict__ W)
{
  int idx = blockIdx.x*256 + threadIdx.x;
  if (idx >= PREP_TOT) return;
  float v;
  if      (idx <  24576){ int t=idx;        int n=t/192,k=t%192; v=(k<168)? w1l[k*128+n]:0.f; }
  else if (idx <  49152){ int t=idx- 24576; int n=t/192,k=t%192; v=(k<168)? w1r[k*128+n]:0.f; }
  else if (idx <  65536){ int t=idx- 49152; int n=t/128,k=t%128; v=w2l[k*128+n]; }
  else if (idx <  81920){ int t=idx- 65536; int n=t/128,k=t%128; v=w2r[k*128+n]; }
  else if (idx <  90112){ int t=idx- 81920; int n=t/128,k=t%128; v=w3l[k*64+n]; }
  else if (idx <  98304){ int t=idx- 90112; int n=t/128,k=t%128; v=w3r[k*64+n]; }
  else if (idx < 102400){ int t=idx- 98304; int n=t/64, k=t%64;  v=tcnw[(n*64+k)*2+0]; }
  else if (idx < 106496){ int t=idx-102400; int n=t/64, k=t%64;  v=tcnw[(n*64+k)*2+1]; }
  else if (idx < 110592){ int t=idx-106496; int n=t/64, k=t%64;  v=wq[k*64+n]; }
  else if (idx < 114688){ int t=idx-110592; int n=t/64, k=t%64;  v=wk[k*64+n]; }
  else if (idx < 118784){ int t=idx-114688; int n=t/64, k=t%64;  v=wv[k*64+n]; }
  else if (idx < 122880){ int t=idx-118784; int n=t/64, k=t%64;  v=wo[k*64+n]; }
  else if (idx < 253952){ int t=idx-122880; int kh=t/8192, r=t%8192, n=r/128, k=r%128;
                          v=fc1w[kh*8192 + k*64 + n]; }
  else                  { int t=idx-253952; int kh=t/2048, r=t%2048, n=r/64,  k=r%64;
                          v=(n<24)? fc2w[kh*1536 + k*24 + n] : 0.f; }
  W[idx] = f2bf(v);
}

// ---------------------------------------------------------------------------
// fused GNN + TCN + attention + proj : 1 wg = 8 graphs, 1 wave = 2 graphs.
// ---------------------------------------------------------------------------
__global__ __launch_bounds__(256,3) void k_fused(
  const float* __restrict__ x, const int* __restrict__ edst,
  const float* __restrict__ b1, const float* __restrict__ b2,
  const float* __restrict__ b3, const float* __restrict__ tcnb,
  const float* __restrict__ wo, const float* __restrict__ wproj,
  const float* __restrict__ bproj,
  const unsigned short* __restrict__ ws0, unsigned short* __restrict__ feat)
{
  __shared__ alignas(16) unsigned char pool[4*9216];
  __shared__ alignas(16) unsigned short WB[2][4352];   // 2 x 8704 B slots
  const int tid=threadIdx.x, w=tid>>6, lane=tid&63, quad=lane>>4, l15=lane&15;
  unsigned short* AR = (unsigned short*)(pool + w*9216);
  const int gb0 = (blockIdx.x*4 + w)*2;

  unsigned short* Hb = AR;              // [2][16][136]
  unsigned short* X  = AR;              // [2][16][72]
  unsigned short* T  = AR + 2304;       // [2][16][72]
  unsigned short* Qb = AR;              // [2][16][72]
  unsigned short* Pb = AR + 2304;       // [2][4][16][16]
  float* OMf = (float*)AR;              // [4][64] f32

  const bf16x8 Z = zero8();
  const f32x4  z = {0.f,0.f,0.f,0.f};
  const int laneA = 32*quad + l15, laneB = laneA + 16;

  uint4 rg[2];
  // prologue load issued FIRST: latency hides under adjacency + x staging
  sload<3072>(ws0 + O_W1L, tid, rg);

  // ---- adjacency: A-frags built fully in registers via shuffles ----
  bf16x8 aA[2];
  #pragma unroll
  for (int g=0; g<2; ++g){
    int dl = edst[(gb0+g)*64 + lane] & 15;
    float c4[4]; float csum = 0.f;
    #pragma unroll
    for (int ss=0; ss<4; ++ss){
      int s = quad*4 + ss; int cc = 0;
      #pragma unroll
      for (int k=0;k<4;++k) cc += (__shfl(dl, s*4+k, 64) == l15) ? 1 : 0;
      c4[ss] = (float)cc; csum += (float)cc;
    }
    csum += __shfl_xor(csum, 16, 64);
    csum += __shfl_xor(csum, 32, 64);
    float ainv = 1.f / fmaxf(csum, 1.f);
    bf16x8 t = shfrag(pkbf2(c4[0]*ainv, c4[1]*ainv),
                      pkbf2(c4[2]*ainv, c4[3]*ainv), laneA, laneB);
    aA[g] = (quad < 2) ? t : Z;           // exact zeros for k>=16
  }

  // ---- x staged ONCE: 12 A-frags in registers (dead after layer 1) ----
  const float* xr0 = x + (size_t)(gb0*16 + l15)*168;
  const float* xr1 = xr0 + 16*168;
  bf16x8 xa0[6], xa1[6];
  #pragma unroll
  for (int kc=0;kc<6;++kc){
    xa0[kc] = xfrag(xr0, kc*32 + quad*8);
    xa1[kc] = xfrag(xr1, kc*32 + quad*8);
  }

  int cur = 0;
  sstore<3072,192,200>(WB[0], tid, rg);
  __syncthreads();

  // ---- SAGE layer 1: 8 col-groups of 16, phases (W1L cg | W1R cg) ----
  #pragma unroll
  for (int cg=0; cg<8; ++cg){
    // slot: W1L[cg]; prefetch W1R[cg]
    sload<3072>(ws0 + O_W1R + cg*3072, tid, rg);
    f32x4 au0=z, au1_=z;
    #pragma unroll
    for (int kc=0;kc<6;++kc){
      bf16x8 bl = ld8(WB[cur] + l15*200 + kc*32 + quad*8);
      au0  = MFMA16(xa0[kc], bl, au0);
      au1_ = MFMA16(xa1[kc], bl, au1_);
    }
    bf16x8 uf0  = shfrag(pkbf2(au0[0],au0[1]),  pkbf2(au0[2],au0[3]),  laneA, laneB);
    bf16x8 uf1_ = shfrag(pkbf2(au1_[0],au1_[1]), pkbf2(au1_[2],au1_[3]), laneA, laneB);
    PH_NEXT(3072,192,200);

    // slot: W1R[cg]; prefetch next
    if (cg < 7) sload<3072>(ws0 + O_W1L + (cg+1)*3072, tid, rg);
    else        sload<4096>(ws0 + O_W2L, tid, rg);
    f32x4 av0=z, av1_=z;
    #pragma unroll
    for (int kc=0;kc<6;++kc){
      bf16x8 br = ld8(WB[cur] + l15*200 + kc*32 + quad*8);
      av0  = MFMA16(xa0[kc], br, av0);
      av1_ = MFMA16(xa1[kc], br, av1_);
    }
    av0  = MFMA16(aA[0], uf0,  av0);
    av1_ = MFMA16(aA[1], uf1_, av1_);
    {
      float bb = b1[cg*16 + l15];
      #pragma unroll
      for (int r=0;r<4;++r){
        Hb[       (quad*4+r)*136 + cg*16 + l15] = f2bf(fmaxf(av0[r]+bb, 0.f));
        Hb[2176 + (quad*4+r)*136 + cg*16 + l15] = f2bf(fmaxf(av1_[r]+bb, 0.f));
      }
    }
    if (cg < 7){ PH_NEXT(3072,192,200); }
    else       { PH_NEXT(4096,128,136); }
  }
  FENCE();

  // ---- SAGE layer 2: 4 col-groups of 32, phases (W2L cg | W2R cg) ----
  {
    ushort4 os[4][2][2];
    #pragma unroll
    for (int cg=0; cg<4; ++cg){
      // slot W2L[cg]; prefetch W2R[cg]
      sload<4096>(ws0 + O_W2R + cg*4096, tid, rg);
      bf16x8 uf[2][2];
      {
        f32x4 au[2][2] = {{z,z},{z,z}};
        #pragma unroll
        for (int kc=0;kc<4;++kc){
          bf16x8 a0 = ld8(Hb +        l15*136 + kc*32 + quad*8);
          bf16x8 a1 = ld8(Hb + 2176 + l15*136 + kc*32 + quad*8);
          #pragma unroll
          for (int c=0;c<2;++c){
            bf16x8 bl = ld8(WB[cur] + (c*16+l15)*136 + kc*32 + quad*8);
            au[0][c] = MFMA16(a0, bl, au[0][c]);
            au[1][c] = MFMA16(a1, bl, au[1][c]);
          }
        }
        #pragma unroll
        for (int g=0;g<2;++g)
        #pragma unroll
        for (int c=0;c<2;++c)
          uf[g][c] = shfrag(pkbf2(au[g][c][0],au[g][c][1]),
                            pkbf2(au[g][c][2],au[g][c][3]), laneA, laneB);
      }
      PH_NEXT(4096,128,136);

      // slot W2R[cg]; prefetch next
      if (cg < 3) sload<4096>(ws0 + O_W2L + (cg+1)*4096, tid, rg);
      else        sload<4096>(ws0 + O_W3L, tid, rg);
      {
        f32x4 av[2][2] = {{z,z},{z,z}};
        #pragma unroll
        for (int kc=0;kc<4;++kc){
          bf16x8 a0 = ld8(Hb +        l15*136 + kc*32 + quad*8);
          bf16x8 a1 = ld8(Hb + 2176 + l15*136 + kc*32 + quad*8);
          #pragma unroll
          for (int c=0;c<2;++c){
            bf16x8 br = ld8(WB[cur] + (c*16+l15)*136 + kc*32 + quad*8);
            av[0][c] = MFMA16(a0, br, av[0][c]);
            av[1][c] = MFMA16(a1, br, av[1][c]);
          }
        }
        #pragma unroll
        for (int g=0;g<2;++g)
        #pragma unroll
        for (int c=0;c<2;++c)
          av[g][c] = MFMA16(aA[g], uf[g][c], av[g][c]);
        #pragma unroll
        for (int c=0;c<2;++c){
          float bb = b2[cg*32 + c*16 + l15];
          #pragma unroll
          for (int g=0;g<2;++g){
            ushort4 p;
            p.x = f2bf(fmaxf(av[g][c][0]+bb, 0.f));
            p.y = f2bf(fmaxf(av[g][c][1]+bb, 0.f));
            p.z = f2bf(fmaxf(av[g][c][2]+bb, 0.f));
            p.w = f2bf(fmaxf(av[g][c][3]+bb, 0.f));
            os[cg][g][c] = p;
          }
        }
      }
      if (cg == 3){
        // all Hb reads done: in-place writeback (wave-private)
        #pragma unroll
        for (int c2=0;c2<4;++c2)
        #pragma unroll
        for (int g=0;g<2;++g)
        #pragma unroll
        for (int c=0;c<2;++c){
          unsigned short* bp = Hb + g*2176 + c2*32 + c*16 + l15;
          ushort4 p = os[c2][g][c];
          bp[(quad*4+0)*136] = p.x;
          bp[(quad*4+1)*136] = p.y;
          bp[(quad*4+2)*136] = p.z;
          bp[(quad*4+3)*136] = p.w;
        }
        FENCE();
      }
      PH_NEXT(4096,128,136);
    }
  }

  // ---- SAGE layer 3: 4 phases (W3L h0|h1, W3R h0|h1); X written at end ----
  bf16x8 uf3[2][4];
  f32x4  av3[2][4];
  { // slot W3L h0; prefetch W3L h1
    sload<4096>(ws0 + O_W3L + 4096, tid, rg);
    f32x4 au[2][2] = {{z,z},{z,z}};
    #pragma unroll
    for (int kc=0;kc<4;++kc){
      bf16x8 a0 = ld8(Hb +        l15*136 + kc*32 + quad*8);
      bf16x8 a1 = ld8(Hb + 2176 + l15*136 + kc*32 + quad*8);
      #pragma unroll
      for (int c=0;c<2;++c){
        bf16x8 bl = ld8(WB[cur] + (c*16+l15)*136 + kc*32 + quad*8);
        au[0][c] = MFMA16(a0, bl, au[0][c]);
        au[1][c] = MFMA16(a1, bl, au[1][c]);
      }
    }
    #pragma unroll
    for (int g=0;g<2;++g)
    #pragma unroll
    for (int c=0;c<2;++c)
      uf3[g][c] = shfrag(pkbf2(au[g][c][0],au[g][c][1]),
                         pkbf2(au[g][c][2],au[g][c][3]), laneA, laneB);
    PH_NEXT(4096,128,136);
  }
  { // slot W3L h1; prefetch W3R h0
    sload<4096>(ws0 + O_W3R, tid, rg);
    f32x4 au[2][2] = {{z,z},{z,z}};
    #pragma unroll
    for (int kc=0;kc<4;++kc){
      bf16x8 a0 = ld8(Hb +        l15*136 + kc*32 + quad*8);
      bf16x8 a1 = ld8(Hb + 2176 + l15*136 + kc*32 + quad*8);
      #pragma unroll
      for (int c=0;c<2;++c){
        bf16x8 bl = ld8(WB[cur] + (c*16+l15)*136 + kc*32 + quad*8);
        au[0][c] = MFMA16(a0, bl, au[0][c]);
        au[1][c] = MFMA16(a1, bl, au[1][c]);
      }
    }
    #pragma unroll
    for (int g=0;g<2;++g)
    #pragma unroll
    for (int c=0;c<2;++c)
      uf3[g][2+c] = shfrag(pkbf2(au[g][c][0],au[g][c][1]),
                           pkbf2(au[g][c][2],au[g][c][3]), laneA, laneB);
    PH_NEXT(4096,128,136);
  }
  { // slot W3R h0; prefetch W3R h1
    sload<4096>(ws0 + O_W3R + 4096, tid, rg);
    #pragma unroll
    for (int g=0;g<2;++g){ av3[g][0]=z; av3[g][1]=z; }
    #pragma unroll
    for (int kc=0;kc<4;++kc){
      bf16x8 a0 = ld8(Hb +        l15*136 + kc*32 + quad*8);
      bf16x8 a1 = ld8(Hb + 2176 + l15*136 + kc*32 + quad*8);
      #pragma unroll
      for (int c=0;c<2;++c){
        bf16x8 br = ld8(WB[cur] + (c*16+l15)*136 + kc*32 + quad*8);
        av3[0][c] = MFMA16(a0, br, av3[0][c]);
        av3[1][c] = MFMA16(a1, br, av3[1][c]);
      }
    }
    #pragma unroll
    for (int g=0;g<2;++g)
    #pragma unroll
    for (int c=0;c<2;++c)
      av3[g][c] = MFMA16(aA[g], uf3[g][c], av3[g][c]);
    PH_NEXT(4096,128,136);
  }
  { // slot W3R h1; prefetch T0 h0; then write X (all Hb reads complete here)
    sload<2048>(ws0 + O_T0, tid, rg);
    #pragma unroll
    for (int g=0;g<2;++g){ av3[g][2]=z; av3[g][3]=z; }
    #pragma unroll
    for (int kc=0;kc<4;++kc){
      bf16x8 a0 = ld8(Hb +        l15*136 + kc*32 + quad*8);
      bf16x8 a1 = ld8(Hb + 2176 + l15*136 + kc*32 + quad*8);
      #pragma unroll
      for (int c=0;c<2;++c){
        bf16x8 br = ld8(WB[cur] + (c*16+l15)*136 + kc*32 + quad*8);
        av3[0][2+c] = MFMA16(a0, br, av3[0][2+c]);
        av3[1][2+c] = MFMA16(a1, br, av3[1][2+c]);
      }
    }
    #pragma unroll
    for (int g=0;g<2;++g)
    #pragma unroll
    for (int c=0;c<2;++c)
      av3[g][2+c] = MFMA16(aA[g], uf3[g][2+c], av3[g][2+c]);
    #pragma unroll
    for (int c=0;c<4;++c){
      float bb = b3[c*16 + l15];
      #pragma unroll
      for (int g=0;g<2;++g)
      #pragma unroll
      for (int r=0;r<4;++r)
        X[g*1152 + (quad*4+r)*72 + c*16 + l15] = f2bf(av3[g][c][r] + bb);
    }
    FENCE();
    PH_NEXT(2048,64,72);
  }

  // ---- TCN: 4 phases (T0h0, T1h0 -> store cols 0..31; T0h1, T1h1 -> 32..63)
  {
    f32x4 acct[2][2] = {{z,z},{z,z}};
    { // slot T0h0; prefetch T1h0
      sload<2048>(ws0 + O_T1, tid, rg);
      #pragma unroll
      for (int kc=0;kc<2;++kc){
        bf16x8 as0 = (l15>0) ? ld8(X +        (l15-1)*72 + kc*32 + quad*8) : Z;
        bf16x8 as1 = (l15>0) ? ld8(X + 1152 + (l15-1)*72 + kc*32 + quad*8) : Z;
        #pragma unroll
        for (int c=0;c<2;++c){
          bf16x8 w0 = ld8(WB[cur] + (c*16+l15)*72 + kc*32 + quad*8);
          acct[0][c] = MFMA16(as0, w0, acct[0][c]);
          acct[1][c] = MFMA16(as1, w0, acct[1][c]);
        }
      }
      PH_NEXT(2048,64,72);
    }
    { // slot T1h0; prefetch T0h1; finish + store T cols 0..31
      sload<2048>(ws0 + O_T0 + 2048, tid, rg);
      #pragma unroll
      for (int kc=0;kc<2;++kc){
        bf16x8 ax0 = ld8(X +        l15*72 + kc*32 + quad*8);
        bf16x8 ax1 = ld8(X + 1152 + l15*72 + kc*32 + quad*8);
        #pragma unroll
        for (int c=0;c<2;++c){
          bf16x8 w1 = ld8(WB[cur] + (c*16+l15)*72 + kc*32 + quad*8);
          acct[0][c] = MFMA16(ax0, w1, acct[0][c]);
          acct[1][c] = MFMA16(ax1, w1, acct[1][c]);
        }
      }
      #pragma unroll
      for (int c=0;c<2;++c){
        int col = c*16 + l15;
        float tb = tcnb[col];
        #pragma unroll
        for (int g=0;g<2;++g)
        #pragma unroll
        for (int r=0;r<4;++r){
          float xr = bf2f(X[g*1152 + (quad*4+r)*72 + col]);
          T[g*1152 + (quad*4+r)*72 + col] = f2bf(fmaxf(acct[g][c][r]+tb, 0.f) + xr);
        }
      }
      PH_NEXT(2048,64,72);
    }
    f32x4 acc2[2][2] = {{z,z},{z,z}};
    { // slot T0h1; prefetch T1h1
      sload<2048>(ws0 + O_T1 + 2048, tid, rg);
      #pragma unroll
      for (int kc=0;kc<2;++kc){
        bf16x8 as0 = (l15>0) ? ld8(X +        (l15-1)*72 + kc*32 + quad*8) : Z;
        bf16x8 as1 = (l15>0) ? ld8(X + 1152 + (l15-1)*72 + kc*32 + quad*8) : Z;
        #pragma unroll
        for (int c=0;c<2;++c){
          bf16x8 w0 = ld8(WB[cur] + (c*16+l15)*72 + kc*32 + quad*8);
          acc2[0][c] = MFMA16(as0, w0, acc2[0][c]);
          acc2[1][c] = MFMA16(as1, w0, acc2[1][c]);
        }
      }
      PH_NEXT(2048,64,72);
    }
    { // slot T1h1; prefetch WQh0; finish + store T cols 32..63
      sload<2048>(ws0 + O_WQ, tid, rg);
      #pragma unroll
      for (int kc=0;kc<2;++kc){
        bf16x8 ax0 = ld8(X +        l15*72 + kc*32 + quad*8);
        bf16x8 ax1 = ld8(X + 1152 + l15*72 + kc*32 + quad*8);
        #pragma unroll
        for (int c=0;c<2;++c){
          bf16x8 w1 = ld8(WB[cur] + (c*16+l15)*72 + kc*32 + quad*8);
          acc2[0][c] = MFMA16(ax0, w1, acc2[0][c]);
          acc2[1][c] = MFMA16(ax1, w1, acc2[1][c]);
        }
      }
      #pragma unroll
      for (int c=0;c<2;++c){
        int col = 32 + c*16 + l15;
        float tb = tcnb[col];
        #pragma unroll
        for (int g=0;g<2;++g)
        #pragma unroll
        for (int r=0;r<4;++r){
          float xr = bf2f(X[g*1152 + (quad*4+r)*72 + col]);
          T[g*1152 + (quad*4+r)*72 + col] = f2bf(fmaxf(acc2[g][c][r]+tb, 0.f) + xr);
        }
      }
      FENCE();
      PH_NEXT(2048,64,72);
    }
  }

  // ---- Q: 2 phases; Qb (over dead X) ----
  { // slot WQh0; prefetch WQh1
    sload<2048>(ws0 + O_WQ + 2048, tid, rg);
    f32x4 aq[2][2] = {{z,z},{z,z}};
    #pragma unroll
    for (int kc=0;kc<2;++kc){
      bf16x8 t0 = ld8(T +        l15*72 + kc*32 + quad*8);
      bf16x8 t1 = ld8(T + 1152 + l15*72 + kc*32 + quad*8);
      #pragma unroll
      for (int c=0;c<2;++c){
        bf16x8 b = ld8(WB[cur] + (c*16+l15)*72 + kc*32 + quad*8);
        aq[0][c] = MFMA16(t0, b, aq[0][c]);
        aq[1][c] = MFMA16(t1, b, aq[1][c]);
      }
    }
    #pragma unroll
    for (int c=0;c<2;++c)
    #pragma unroll
    for (int g=0;g<2;++g)
    #pragma unroll
    for (int r=0;r<4;++r)
      Qb[g*1152 + (quad*4+r)*72 + c*16 + l15] = f2bf(aq[g][c][r]);
    PH_NEXT(2048,64,72);
  }
  { // slot WQh1; prefetch WKh0
    sload<2048>(ws0 + O_WK, tid, rg);
    f32x4 aq[2][2] = {{z,z},{z,z}};
    #pragma unroll
    for (int kc=0;kc<2;++kc){
      bf16x8 t0 = ld8(T +        l15*72 + kc*32 + quad*8);
      bf16x8 t1 = ld8(T + 1152 + l15*72 + kc*32 + quad*8);
      #pragma unroll
      for (int c=0;c<2;++c){
        bf16x8 b = ld8(WB[cur] + (c*16+l15)*72 + kc*32 + quad*8);
        aq[0][c] = MFMA16(t0, b, aq[0][c]);
        aq[1][c] = MFMA16(t1, b, aq[1][c]);
      }
    }
    #pragma unroll
    for (int c=0;c<2;++c)
    #pragma unroll
    for (int g=0;g<2;++g)
    #pragma unroll
    for (int r=0;r<4;++r)
      Qb[g*1152 + (quad*4+r)*72 + 32 + c*16 + l15] = f2bf(aq[g][c][r]);
    PH_NEXT(2048,64,72);
  }

  // ---- K^T: 2 phases; swapped operands -> bK frags ----
  bf16x8 bK[2][4];
  {
    f32x4 kt[2][4];
    { // slot WKh0; prefetch WKh1
      sload<2048>(ws0 + O_WK + 2048, tid, rg);
      #pragma unroll
      for (int g=0;g<2;++g){ kt[g][0]=z; kt[g][1]=z; }
      #pragma unroll
      for (int kc=0;kc<2;++kc){
        bf16x8 t0 = ld8(T +        l15*72 + kc*32 + quad*8);
        bf16x8 t1 = ld8(T + 1152 + l15*72 + kc*32 + quad*8);
        #pragma unroll
        for (int c=0;c<2;++c){
          bf16x8 aW = ld8(WB[cur] + (c*16+l15)*72 + kc*32 + quad*8);
          kt[0][c] = MFMA16(aW, t0, kt[0][c]);
          kt[1][c] = MFMA16(aW, t1, kt[1][c]);
        }
      }
      PH_NEXT(2048,64,72);
    }
    { // slot WKh1; prefetch WVh0
      sload<2048>(ws0 + O_WV, tid, rg);
      #pragma unroll
      for (int g=0;g<2;++g){ kt[g][2]=z; kt[g][3]=z; }
      #pragma unroll
      for (int kc=0;kc<2;++kc){
        bf16x8 t0 = ld8(T +        l15*72 + kc*32 + quad*8);
        bf16x8 t1 = ld8(T + 1152 + l15*72 + kc*32 + quad*8);
        #pragma unroll
        for (int c=0;c<2;++c){
          bf16x8 aW = ld8(WB[cur] + (c*16+l15)*72 + kc*32 + quad*8);
          kt[0][2+c] = MFMA16(aW, t0, kt[0][2+c]);
          kt[1][2+c] = MFMA16(aW, t1, kt[1][2+c]);
        }
      }
      #pragma unroll
      for (int g=0;g<2;++g)
      #pragma unroll
      for (int c=0;c<4;++c){
        bf16x8 f = shfrag(pkbf2(kt[g][c][0],kt[g][c][1]),
                          pkbf2(kt[g][c][2],kt[g][c][3]), laneA, laneB);
        bK[g][c] = (quad < 2) ? f : Z;     // K padded 16->32: zero upper half
      }
      PH_NEXT(2048,64,72);
    }
  }

  // ---- V: 2 phases; C-layout -> bV frags ----
  bf16x8 bV[2][4];
  {
    f32x4 vv[2][4];
    { // slot WVh0; prefetch WVh1
      sload<2048>(ws0 + O_WV + 2048, tid, rg);
      #pragma unroll
      for (int g=0;g<2;++g){ vv[g][0]=z; vv[g][1]=z; }
      #pragma unroll
      for (int kc=0;kc<2;++kc){
        bf16x8 t0 = ld8(T +        l15*72 + kc*32 + quad*8);
        bf16x8 t1 = ld8(T + 1152 + l15*72 + kc*32 + quad*8);
        #pragma unroll
        for (int c=0;c<2;++c){
          bf16x8 b = ld8(WB[cur] + (c*16+l15)*72 + kc*32 + quad*8);
          vv[0][c] = MFMA16(t0, b, vv[0][c]);
          vv[1][c] = MFMA16(t1, b, vv[1][c]);
        }
      }
      PH_NEXT(2048,64,72);
    }
    { // slot WVh1 (last phase; no prefetch)
      #pragma unroll
      for (int g=0;g<2;++g){ vv[g][2]=z; vv[g][3]=z; }
      #pragma unroll
      for (int kc=0;kc<2;++kc){
        bf16x8 t0 = ld8(T +        l15*72 + kc*32 + quad*8);
        bf16x8 t1 = ld8(T + 1152 + l15*72 + kc*32 + quad*8);
        #pragma unroll
        for (int c=0;c<2;++c){
          bf16x8 b = ld8(WB[cur] + (c*16+l15)*72 + kc*32 + quad*8);
          vv[0][2+c] = MFMA16(t0, b, vv[0][2+c]);
          vv[1][2+c] = MFMA16(t1, b, vv[1][2+c]);
        }
      }
      #pragma unroll
      for (int g=0;g<2;++g)
      #pragma unroll
      for (int c=0;c<4;++c)
        bV[g][c] = shfrag(pkbf2(vv[g][c][0],vv[g][c][1]),
                          pkbf2(vv[g][c][2],vv[g][c][3]), laneA, laneB);
    }
  }
  FENCE();   // all T reads done; Pb (over T) safe to write

  // ---- S = (Q K^T)/4 per head; softmax across l15 lanes -> Pb ----
  #pragma unroll
  for (int g=0; g<2; ++g){
    unsigned short* Pbg = Pb + g*1024;
    #pragma unroll
    for (int h=0;h<4;++h){
      bf16x8 aQ = (quad < 2) ? ld8(Qb + g*1152 + l15*72 + h*16 + quad*8) : Z;
      f32x4 s4 = MFMA16(aQ, bK[g][h], z);
      #pragma unroll
      for (int r=0;r<4;++r){
        float s = s4[r]*0.25f;
        float m = s;
        m = fmaxf(m, __shfl_xor(m,1,64));
        m = fmaxf(m, __shfl_xor(m,2,64));
        m = fmaxf(m, __shfl_xor(m,4,64));
        m = fmaxf(m, __shfl_xor(m,8,64));
        float p = __expf(s-m);
        float su = p;
        su += __shfl_xor(su,1,64);
        su += __shfl_xor(su,2,64);
        su += __shfl_xor(su,4,64);
        su += __shfl_xor(su,8,64);
        Pbg[(h*16 + quad*4 + r)*16 + l15] = f2bf(p/su);
      }
    }
  }
  FENCE();

  // ---- O = P@V per head; column mean over 16 nodes in-register -> OM ----
  #pragma unroll
  for (int g=0; g<2; ++g){
    unsigned short* Pbg = Pb + g*1024;
    #pragma unroll
    for (int h=0;h<4;++h){
      bf16x8 aP = (quad < 2) ? ld8(Pbg + (h*16 + l15)*16 + quad*8) : Z;
      f32x4 o = MFMA16(aP, bV[g][h], z);
      float cs = o[0]+o[1]+o[2]+o[3];
      cs += __shfl_xor(cs, 16, 64);
      cs += __shfl_xor(cs, 32, 64);
      if (quad == 0) OMf[g*64 + h*16 + l15] = cs * (1.f/16.f);
    }
  }
  FENCE();

  // ---- feat = ((mean O) @ wo) @ wproj + bproj  (all fp32 scalar) ----
  {
    float t0 = 0.f, t1 = 0.f;
    #pragma unroll 8
    for (int d=0; d<64; ++d){
      float wv = wo[d*64 + lane];
      t0 += OMf[d]    * wv;
      t1 += OMf[64+d] * wv;
    }
    OMf[128+lane] = t0;
    OMf[192+lane] = t1;
    FENCE();
    float a00 = bproj[lane], a01 = bproj[lane+64];
    float a10 = a00, a11 = a01;
    #pragma unroll 8
    for (int m=0; m<64; ++m){
      float f0 = OMf[128+m], f1 = OMf[192+m];
      float w0 = wproj[m*128 + lane], w1 = wproj[m*128 + lane + 64];
      a00 += f0*w0; a01 += f0*w1;
      a10 += f1*w0; a11 += f1*w1;
    }
    feat[(size_t)gb0*128 + lane]        = f2bf(a00);
    feat[(size_t)gb0*128 + lane + 64]   = f2bf(a01);
    feat[(size_t)(gb0+1)*128 + lane]      = f2bf(a10);
    feat[(size_t)(gb0+1)*128 + lane + 64] = f2bf(a11);
  }
}

// ---------------------------------------------------------------------------
// per-variable fc heads: 1 wg = 1 kh; W1/W2 in padded LDS; pred written via
// LDS transpose as coalesced bursts; y-copy fused at tail.
// ---------------------------------------------------------------------------
__global__ __launch_bounds__(256,4) void k_heads(
  const unsigned short* __restrict__ ws0,
  const float* __restrict__ fc1b, const float* __restrict__ fc2b,
  float* __restrict__ pred,
  const float4* __restrict__ ysrc, float4* __restrict__ ydst)
{
  __shared__ alignas(16) unsigned short W1s[64*136];
  __shared__ alignas(16) unsigned short W2s[32*72];
  __shared__ alignas(16) unsigned short hh[4*2304];
  const int tid=threadIdx.x, w=tid>>6, lane=tid&63, quad=lane>>4, l15=lane&15;
  const int kh = blockIdx.x >> 7;
  const int rb = (blockIdx.x & 127)*128 + w*32;   // this wave's 32 rows
  unsigned short* hw = hh + w*2304;
  const unsigned short* featg = ws0 + O_FEAT;
  const unsigned short* W1 = ws0 + O_FC1 + kh*8192;
  const unsigned short* W2 = ws0 + O_FC2 + kh*2048;

  #pragma unroll
  for (int it=0; it<4; ++it){
    int idx = it*2048 + tid*8;
    int row = idx >> 7, col = idx & 127;
    *(uint4*)(W1s + row*136 + col) = *(const uint4*)(W1 + idx);
  }
  {
    int idx = tid*8; int row = idx >> 6, col = idx & 63;
    *(uint4*)(W2s + row*72 + col) = *(const uint4*)(W2 + idx);
  }
  __syncthreads();

  f32x4 z = {0.f,0.f,0.f,0.f};
  f32x4 acc[2][4];
  #pragma unroll
  for (int t=0;t<2;++t)
  #pragma unroll
  for (int c=0;c<4;++c) acc[t][c]=z;
  #pragma unroll
  for (int kc=0;kc<4;++kc){
    bf16x8 a0 = ld8(featg + (size_t)(rb+l15)*128    + kc*32+quad*8);
    bf16x8 a1 = ld8(featg + (size_t)(rb+16+l15)*128 + kc*32+quad*8);
    #pragma unroll
    for (int c=0;c<4;++c){
      bf16x8 b = ld8(W1s + (c*16+l15)*136 + kc*32+quad*8);
      acc[0][c] = MFMA16(a0, b, acc[0][c]);
      acc[1][c] = MFMA16(a1, b, acc[1][c]);
    }
  }
  #pragma unroll
  for (int c=0;c<4;++c){
    float bb = fc1b[kh*64 + c*16+l15];
    #pragma unroll
    for (int t=0;t<2;++t)
    #pragma unroll
    for (int r=0;r<4;++r)
      hw[t*1152 + (quad*4+r)*72 + c*16+l15] = f2bf(fmaxf(acc[t][c][r]+bb, 0.f));
  }
  FENCE();
  f32x4 acc2[2][2];
  #pragma unroll
  for (int t=0;t<2;++t)
  #pragma unroll
  for (int c=0;c<2;++c) acc2[t][c]=z;
  #pragma unroll
  for (int kc=0;kc<2;++kc){
    bf16x8 a0 = ld8(hw +        l15*72 + kc*32+quad*8);
    bf16x8 a1 = ld8(hw + 1152 + l15*72 + kc*32+quad*8);
    #pragma unroll
    for (int c=0;c<2;++c){
      bf16x8 b = ld8(W2s + (c*16+l15)*72 + kc*32+quad*8);
      acc2[0][c] = MFMA16(a0, b, acc2[0][c]);
      acc2[1][c] = MFMA16(a1, b, acc2[1][c]);
    }
  }
  FENCE();   // all hw reads done; reuse hw as f32 staging for coalesced writes
  float* hf = (float*)hw;     // 1152 floats; we use 384 per tile
  #pragma unroll
  for (int t=0;t<2;++t){
    #pragma unroll
    for (int c=0;c<2;++c){
      int col = c*16+l15;
      if (col < 24){
        float bb = fc2b[kh*24+col];
        #pragma unroll
        for (int r=0;r<4;++r)
          hf[(quad*4+r)*24 + col] = acc2[t][c][r] + bb;
      }
    }
    FENCE();
    float* pb = pred + (size_t)kh*393216 + (size_t)(rb + t*16)*24;
    #pragma unroll
    for (int k=0;k<6;++k)
      pb[k*64 + lane] = hf[k*64 + lane];
    FENCE();
  }

  // fused yb copy: 2048 blocks x 256 threads x 3 = 1572864 float4 exact
  {
    int gidx = blockIdx.x*256 + tid;
    #pragma unroll
    for (int k=0;k<3;++k)
      ydst[gidx + k*524288] = ysrc[gidx + k*524288];
  }
}

// ---------------------------------------------------------------------------
extern "C" void kernel_launch(void* const* d_in, const int* in_sizes, int n_in,
                              void* d_out, int out_size, void* d_ws, size_t ws_size,
                              hipStream_t stream) {
  const float* x    = (const float*)d_in[0];
  const float* y    = (const float*)d_in[1];
  const int*   ei   = (const int*)d_in[2];
  const float* w1l  = (const float*)d_in[4];
  const float* w1r  = (const float*)d_in[5];
  const float* b1   = (const float*)d_in[6];
  const float* w2l  = (const float*)d_in[7];
  const float* w2r  = (const float*)d_in[8];
  const float* b2   = (const float*)d_in[9];
  const float* w3l  = (const float*)d_in[10];
  const float* w3r  = (const float*)d_in[11];
  const float* b3   = (const float*)d_in[12];
  const float* tcnw = (const float*)d_in[13];
  const float* tcnb = (const float*)d_in[14];
  const float* wq   = (const float*)d_in[15];
  const float* wk   = (const float*)d_in[16];
  const float* wv   = (const float*)d_in[17];
  const float* wo   = (const float*)d_in[18];
  const float* wpr  = (const float*)d_in[19];
  const float* bpr  = (const float*)d_in[20];
  const float* fc1w = (const float*)d_in[21];
  const float* fc1b = (const float*)d_in[22];
  const float* fc2w = (const float*)d_in[23];
  const float* fc2b = (const float*)d_in[24];

  unsigned short* W = (unsigned short*)d_ws;
  float* out = (float*)d_out;

  k_prep<<<1120, 256, 0, stream>>>(w1l,w1r,w2l,w2r,w3l,w3r,tcnw,wq,wk,wv,wo,fc1w,fc2w,W);
  k_fused<<<NGR/8, 256, 0, stream>>>(x, ei + EDGES, b1,b2,b3,tcnb, wo, wpr, bpr, W, W + O_FEAT);
  k_heads<<<2048, 256, 0, stream>>>(W, fc1b, fc2b, out,
                                    (const float4*)y, (float4*)(out + PRED_ELEMS));
}

// Round 10
// 458.484 us; speedup vs baseline: 1.1257x; 1.1257x over previous
//
#include <hip/hip_runtime.h>
#include <cstdint>
#include <cstddef>

// ---------------------------------------------------------------------------
// SSTAFormer round 12: async weight staging via global_load_lds + source-side
// bank swizzle. Base = round-7/9 structure (best: 225 us k_fused).
//   - r11 lesson: reg-staged double-buffer spills (WRITE 30MB) and regresses.
//   - Now: per phase, ISSUE global_load_lds for the NEXT weight chunk into
//     WB[cur^1] (no VGPRs, no ds_write), compute from WB[cur], then the
//     compiler's vmcnt(0)-before-barrier drain lands AFTER the hiding compute
//     (T3 2-phase pattern, m97). 33 phases.
//   - global_load_lds writes LDS linearly (no padding possible) -> k_prep
//     pre-swizzles each row's 16B chunks by chunk^=(row&7); reads use
//     chunk^(l15&7): lanes 0..7 span all 32 banks (T2 via m173 pattern).
//   - WB = 2 x 4096 u16 slots; LDS 36864+16384 = 53248 B -> 3 wg/CU.
// ---------------------------------------------------------------------------

typedef __attribute__((ext_vector_type(8))) __bf16 bf16x8;
typedef __attribute__((ext_vector_type(4))) float  f32x4;

#define MFMA16(a,b,c) __builtin_amdgcn_mfma_f32_16x16x32_bf16((a),(b),(c),0,0,0)
#define FENCE() __threadfence_block()

#define NGR    16384
#define EDGES  1048576
#define PRED_ELEMS (16*16384*24)

// workspace layout in ushort units (k_fused weights now chunk-swizzled)
#define O_W1L 0               // [128][192]
#define O_W1R 24576
#define O_W2L 49152           // [128][128]
#define O_W2R 65536
#define O_W3L 81920           // [64][128]
#define O_W3R 90112
#define O_T0  98304           // [64 co][64 ci]  (tcn_w[...,0])
#define O_T1  102400
#define O_WQ  106496          // [64][64]
#define O_WK  110592
#define O_WV  114688
#define O_WO  118784
#define O_FC1 122880          // 16 x [64][128]
#define O_FC2 253952          // 16 x [32][64]
#define O_FEAT 286720         // [16384][128] bf16
#define PREP_TOT 286720

static __device__ __forceinline__ unsigned short f2bf(float f){
  unsigned int u = __builtin_bit_cast(unsigned int, f);
  u += 0x7FFFu + ((u >> 16) & 1u);            // RNE
  return (unsigned short)(u >> 16);
}
static __device__ __forceinline__ float bf2f(unsigned short h){
  return __builtin_bit_cast(float, (unsigned int)h << 16);
}
static __device__ __forceinline__ bf16x8 ld8(const unsigned short* p){
  return __builtin_bit_cast(bf16x8, *(const uint4*)p);   // 16B aligned by construction
}
static __device__ __forceinline__ bf16x8 zero8(){
  uint4 u = make_uint4(0u,0u,0u,0u);
  return __builtin_bit_cast(bf16x8, u);
}
static __device__ __forceinline__ unsigned int pkbf2(float a, float b){
  return (unsigned int)f2bf(a) | ((unsigned int)f2bf(b)<<16);
}
static __device__ __forceinline__ bf16x8 u4bf(unsigned int a, unsigned int b,
                                              unsigned int c, unsigned int d){
  uint4 u = make_uint4(a,b,c,d);
  return __builtin_bit_cast(bf16x8, u);
}
// C-layout (row=4*quad'+r, col=l15) -> B-frag (k=8*quad+e, col=l15)
static __device__ __forceinline__ bf16x8 shfrag(unsigned int p0, unsigned int p1,
                                                int laneA, int laneB){
  return u4bf((unsigned int)__shfl((int)p0, laneA, 64),
              (unsigned int)__shfl((int)p1, laneA, 64),
              (unsigned int)__shfl((int)p0, laneB, 64),
              (unsigned int)__shfl((int)p1, laneB, 64));
}
// A-fragment from global fp32 x row (K padded 168->192, W rows >=168 are zero)
static __device__ __forceinline__ bf16x8 xfrag(const float* __restrict__ xrow, int k0){
  int ks = (k0 < 168) ? k0 : 0;          // clamped lanes multiply zero W rows
  float4 f0 = *(const float4*)(xrow + ks);
  float4 f1 = *(const float4*)(xrow + ks + 4);
  return u4bf(pkbf2(f0.x,f0.y), pkbf2(f0.z,f0.w),
              pkbf2(f1.x,f1.y), pkbf2(f1.z,f1.w));
}
// async stage: TOT ushorts, linear LDS dest (wave-uniform base + lane*16B).
// Each instr moves 64 lanes x 16B = 1024B per wave; 4 waves = 4096B/round.
template<int TOT>
static __device__ __forceinline__ void stageG(const unsigned short* __restrict__ src,
                                              unsigned short* __restrict__ dst,
                                              int w, int lane){
  #pragma unroll
  for (int i=0;i<TOT/2048;++i)
    __builtin_amdgcn_global_load_lds(src + i*2048 + w*512 + lane*8,
                                     dst + i*2048 + w*512, 16, 0, 0);
  if constexpr ((TOT & 2047) != 0){
    if (w < (TOT & 2047)/512)          // wave-uniform predicate
      __builtin_amdgcn_global_load_lds(src + (TOT/2048)*2048 + w*512 + lane*8,
                                       dst + (TOT/2048)*2048 + w*512, 16, 0, 0);
  }
}
// swizzled read from staged slot: logical (row, 16B-chunk) -> chunk^(row&7)
static __device__ __forceinline__ bf16x8 ldw(const unsigned short* slot, int K,
                                             int row, int chunk){
  return ld8(slot + row*K + (((chunk) ^ (row & 7)) << 3));
}

// ---------------------------------------------------------------------------
// weight prep: k_fused matrices stored with chunk^=(row&7) swizzle so a
// LINEAR global_load_lds lands them bank-spread; FC1/FC2/WO unchanged.
// ---------------------------------------------------------------------------
__global__ __launch_bounds__(256) void k_prep(
  const float* __restrict__ w1l, const float* __restrict__ w1r,
  const float* __restrict__ w2l, const float* __restrict__ w2r,
  const float* __restrict__ w3l, const float* __restrict__ w3r,
  const float* __restrict__ tcnw,
  const float* __restrict__ wq, const float* __restrict__ wk,
  const float* __restrict__ wv, const float* __restrict__ wo,
  const float* __restrict__ fc1w, const float* __restrict__ fc2w,
  unsigned short* __restrict__ W)
{
  int idx = blockIdx.x*256 + threadIdx.x;
  if (idx >= PREP_TOT) return;
  float v;
  if      (idx <  24576){ int t=idx;        int n=t/192, ks=t%192;
                          int k=(((ks>>3)^(n&7))<<3)+(ks&7);
                          v=(k<168)? w1l[k*128+n]:0.f; }
  else if (idx <  49152){ int t=idx- 24576; int n=t/192, ks=t%192;
                          int k=(((ks>>3)^(n&7))<<3)+(ks&7);
                          v=(k<168)? w1r[k*128+n]:0.f; }
  else if (idx <  65536){ int t=idx- 49152; int n=t/128, ks=t%128;
                          int k=(((ks>>3)^(n&7))<<3)+(ks&7); v=w2l[k*128+n]; }
  else if (idx <  81920){ int t=idx- 65536; int n=t/128, ks=t%128;
                          int k=(((ks>>3)^(n&7))<<3)+(ks&7); v=w2r[k*128+n]; }
  else if (idx <  90112){ int t=idx- 81920; int n=t/128, ks=t%128;
                          int k=(((ks>>3)^(n&7))<<3)+(ks&7); v=w3l[k*64+n]; }
  else if (idx <  98304){ int t=idx- 90112; int n=t/128, ks=t%128;
                          int k=(((ks>>3)^(n&7))<<3)+(ks&7); v=w3r[k*64+n]; }
  else if (idx < 102400){ int t=idx- 98304; int n=t/64, ks=t%64;
                          int k=(((ks>>3)^(n&7))<<3)+(ks&7); v=tcnw[(n*64+k)*2+0]; }
  else if (idx < 106496){ int t=idx-102400; int n=t/64, ks=t%64;
                          int k=(((ks>>3)^(n&7))<<3)+(ks&7); v=tcnw[(n*64+k)*2+1]; }
  else if (idx < 110592){ int t=idx-106496; int n=t/64, ks=t%64;
                          int k=(((ks>>3)^(n&7))<<3)+(ks&7); v=wq[k*64+n]; }
  else if (idx < 114688){ int t=idx-110592; int n=t/64, ks=t%64;
                          int k=(((ks>>3)^(n&7))<<3)+(ks&7); v=wk[k*64+n]; }
  else if (idx < 118784){ int t=idx-114688; int n=t/64, ks=t%64;
                          int k=(((ks>>3)^(n&7))<<3)+(ks&7); v=wv[k*64+n]; }
  else if (idx < 122880){ int t=idx-118784; int n=t/64, k=t%64;  v=wo[k*64+n]; }
  else if (idx < 253952){ int t=idx-122880; int kh=t/8192, r=t%8192, n=r/128, k=r%128;
                          v=fc1w[kh*8192 + k*64 + n]; }
  else                  { int t=idx-253952; int kh=t/2048, r=t%2048, n=r/64,  k=r%64;
                          v=(n<24)? fc2w[kh*1536 + k*24 + n] : 0.f; }
  W[idx] = f2bf(v);
}

// ---------------------------------------------------------------------------
// fused GNN + TCN + attention + proj : 1 wg = 8 graphs, 1 wave = 2 graphs.
// Per phase: issue NEXT stage (global_load_lds -> WB[cur^1]), compute from
// WB[cur], barrier (vmcnt drain hidden behind compute), flip.
// ---------------------------------------------------------------------------
__global__ __launch_bounds__(256,3) void k_fused(
  const float* __restrict__ x, const int* __restrict__ edst,
  const float* __restrict__ b1, const float* __restrict__ b2,
  const float* __restrict__ b3, const float* __restrict__ tcnb,
  const float* __restrict__ wo, const float* __restrict__ wproj,
  const float* __restrict__ bproj,
  const unsigned short* __restrict__ ws0, unsigned short* __restrict__ feat)
{
  __shared__ alignas(16) unsigned char pool[4*9216];
  __shared__ alignas(16) unsigned short WB[2][4096];   // 2 x 8192 B slots
  const int tid=threadIdx.x, w=tid>>6, lane=tid&63, quad=lane>>4, l15=lane&15;
  unsigned short* AR = (unsigned short*)(pool + w*9216);
  const int gb0 = (blockIdx.x*4 + w)*2;

  unsigned short* Hb = AR;              // [2][16][136]
  unsigned short* X  = AR;              // [2][16][72]
  unsigned short* T  = AR + 2304;       // [2][16][72]
  unsigned short* Qb = AR;              // [2][16][72]
  unsigned short* Pb = AR + 2304;       // [2][4][16][16]
  float* OMf = (float*)AR;              // [4][64] f32

  const bf16x8 Z = zero8();
  const f32x4  z = {0.f,0.f,0.f,0.f};
  const int laneA = 32*quad + l15, laneB = laneA + 16;
  const int lx = l15 & 7;               // row&7 for swizzled reads

  int cur = 0;
  // prologue: issue W1L[cg=0]; latency hides under adjacency + x staging
  stageG<3072>(ws0 + O_W1L, WB[0], w, lane);

  // ---- adjacency: A-frags built fully in registers via shuffles ----
  bf16x8 aA[2];
  #pragma unroll
  for (int g=0; g<2; ++g){
    int dl = edst[(gb0+g)*64 + lane] & 15;
    float c4[4]; float csum = 0.f;
    #pragma unroll
    for (int ss=0; ss<4; ++ss){
      int s = quad*4 + ss; int cc = 0;
      #pragma unroll
      for (int k=0;k<4;++k) cc += (__shfl(dl, s*4+k, 64) == l15) ? 1 : 0;
      c4[ss] = (float)cc; csum += (float)cc;
    }
    csum += __shfl_xor(csum, 16, 64);
    csum += __shfl_xor(csum, 32, 64);
    float ainv = 1.f / fmaxf(csum, 1.f);
    bf16x8 t = shfrag(pkbf2(c4[0]*ainv, c4[1]*ainv),
                      pkbf2(c4[2]*ainv, c4[3]*ainv), laneA, laneB);
    aA[g] = (quad < 2) ? t : Z;           // exact zeros for k>=16
  }

  // ---- x staged ONCE: 12 A-frags in registers (dead after layer 1) ----
  const float* xr0 = x + (size_t)(gb0*16 + l15)*168;
  const float* xr1 = xr0 + 16*168;
  bf16x8 xa0[6], xa1[6];
  #pragma unroll
  for (int kc=0;kc<6;++kc){
    xa0[kc] = xfrag(xr0, kc*32 + quad*8);
    xa1[kc] = xfrag(xr1, kc*32 + quad*8);
  }
  __syncthreads();                       // prologue stage complete

  // ---- SAGE layer 1: 8 col-groups of 16 (row = l15, K=192) ----
  #pragma unroll
  for (int cg=0; cg<8; ++cg){
    // phase A: slot=W1L[cg]; issue W1R[cg]
    stageG<3072>(ws0 + O_W1R + cg*3072, WB[cur^1], w, lane);
    f32x4 au0=z, au1_=z;
    #pragma unroll
    for (int kc=0;kc<6;++kc){
      bf16x8 bl = ldw(WB[cur], 192, l15, kc*4+quad);
      au0  = MFMA16(xa0[kc], bl, au0);
      au1_ = MFMA16(xa1[kc], bl, au1_);
    }
    bf16x8 uf0  = shfrag(pkbf2(au0[0],au0[1]),   pkbf2(au0[2],au0[3]),   laneA, laneB);
    bf16x8 uf1_ = shfrag(pkbf2(au1_[0],au1_[1]), pkbf2(au1_[2],au1_[3]), laneA, laneB);
    __syncthreads(); cur ^= 1;

    // phase B: slot=W1R[cg]; issue next
    if (cg < 7) stageG<3072>(ws0 + O_W1L + (cg+1)*3072, WB[cur^1], w, lane);
    else        stageG<4096>(ws0 + O_W2L,               WB[cur^1], w, lane);
    f32x4 av0=z, av1_=z;
    #pragma unroll
    for (int kc=0;kc<6;++kc){
      bf16x8 br = ldw(WB[cur], 192, l15, kc*4+quad);
      av0  = MFMA16(xa0[kc], br, av0);
      av1_ = MFMA16(xa1[kc], br, av1_);
    }
    av0  = MFMA16(aA[0], uf0,  av0);
    av1_ = MFMA16(aA[1], uf1_, av1_);
    {
      float bb = b1[cg*16 + l15];
      #pragma unroll
      for (int r=0;r<4;++r){
        Hb[       (quad*4+r)*136 + cg*16 + l15] = f2bf(fmaxf(av0[r]+bb, 0.f));
        Hb[2176 + (quad*4+r)*136 + cg*16 + l15] = f2bf(fmaxf(av1_[r]+bb, 0.f));
      }
    }
    __syncthreads(); cur ^= 1;
  }
  FENCE();

  // ---- SAGE layer 2: 4 col-groups of 32 (K=128) ----
  {
    ushort4 os[4][2][2];
    #pragma unroll
    for (int cg=0; cg<4; ++cg){
      // phase: slot=W2L[cg]; issue W2R[cg]
      stageG<4096>(ws0 + O_W2R + cg*4096, WB[cur^1], w, lane);
      bf16x8 uf[2][2];
      {
        f32x4 au[2][2] = {{z,z},{z,z}};
        #pragma unroll
        for (int kc=0;kc<4;++kc){
          bf16x8 a0 = ld8(Hb +        l15*136 + kc*32 + quad*8);
          bf16x8 a1 = ld8(Hb + 2176 + l15*136 + kc*32 + quad*8);
          #pragma unroll
          for (int c=0;c<2;++c){
            bf16x8 bl = ldw(WB[cur], 128, c*16+l15, kc*4+quad);
            au[0][c] = MFMA16(a0, bl, au[0][c]);
            au[1][c] = MFMA16(a1, bl, au[1][c]);
          }
        }
        #pragma unroll
        for (int g=0;g<2;++g)
        #pragma unroll
        for (int c=0;c<2;++c)
          uf[g][c] = shfrag(pkbf2(au[g][c][0],au[g][c][1]),
                            pkbf2(au[g][c][2],au[g][c][3]), laneA, laneB);
      }
      __syncthreads(); cur ^= 1;

      // phase: slot=W2R[cg]; issue next
      if (cg < 3) stageG<4096>(ws0 + O_W2L + (cg+1)*4096, WB[cur^1], w, lane);
      else        stageG<4096>(ws0 + O_W3L,               WB[cur^1], w, lane);
      {
        f32x4 av[2][2] = {{z,z},{z,z}};
        #pragma unroll
        for (int kc=0;kc<4;++kc){
          bf16x8 a0 = ld8(Hb +        l15*136 + kc*32 + quad*8);
          bf16x8 a1 = ld8(Hb + 2176 + l15*136 + kc*32 + quad*8);
          #pragma unroll
          for (int c=0;c<2;++c){
            bf16x8 br = ldw(WB[cur], 128, c*16+l15, kc*4+quad);
            av[0][c] = MFMA16(a0, br, av[0][c]);
            av[1][c] = MFMA16(a1, br, av[1][c]);
          }
        }
        #pragma unroll
        for (int g=0;g<2;++g)
        #pragma unroll
        for (int c=0;c<2;++c)
          av[g][c] = MFMA16(aA[g], uf[g][c], av[g][c]);
        #pragma unroll
        for (int c=0;c<2;++c){
          float bb = b2[cg*32 + c*16 + l15];
          #pragma unroll
          for (int g=0;g<2;++g){
            ushort4 p;
            p.x = f2bf(fmaxf(av[g][c][0]+bb, 0.f));
            p.y = f2bf(fmaxf(av[g][c][1]+bb, 0.f));
            p.z = f2bf(fmaxf(av[g][c][2]+bb, 0.f));
            p.w = f2bf(fmaxf(av[g][c][3]+bb, 0.f));
            os[cg][g][c] = p;
          }
        }
      }
      if (cg == 3){
        // all Hb reads of layer 2 done: in-place writeback (wave-private)
        #pragma unroll
        for (int c2=0;c2<4;++c2)
        #pragma unroll
        for (int g=0;g<2;++g)
        #pragma unroll
        for (int c=0;c<2;++c){
          unsigned short* bp = Hb + g*2176 + c2*32 + c*16 + l15;
          ushort4 p = os[c2][g][c];
          bp[(quad*4+0)*136] = p.x;
          bp[(quad*4+1)*136] = p.y;
          bp[(quad*4+2)*136] = p.z;
          bp[(quad*4+3)*136] = p.w;
        }
        FENCE();
      }
      __syncthreads(); cur ^= 1;
    }
  }

  // ---- SAGE layer 3: 4 phases (W3L h0|h1, W3R h0|h1, K=128) ----
  bf16x8 uf3[2][4];
  f32x4  av3[2][4];
  { // slot W3L h0; issue W3L h1
    stageG<4096>(ws0 + O_W3L + 4096, WB[cur^1], w, lane);
    f32x4 au[2][2] = {{z,z},{z,z}};
    #pragma unroll
    for (int kc=0;kc<4;++kc){
      bf16x8 a0 = ld8(Hb +        l15*136 + kc*32 + quad*8);
      bf16x8 a1 = ld8(Hb + 2176 + l15*136 + kc*32 + quad*8);
      #pragma unroll
      for (int c=0;c<2;++c){
        bf16x8 bl = ldw(WB[cur], 128, c*16+l15, kc*4+quad);
        au[0][c] = MFMA16(a0, bl, au[0][c]);
        au[1][c] = MFMA16(a1, bl, au[1][c]);
      }
    }
    #pragma unroll
    for (int g=0;g<2;++g)
    #pragma unroll
    for (int c=0;c<2;++c)
      uf3[g][c] = shfrag(pkbf2(au[g][c][0],au[g][c][1]),
                         pkbf2(au[g][c][2],au[g][c][3]), laneA, laneB);
    __syncthreads(); cur ^= 1;
  }
  { // slot W3L h1; issue W3R h0
    stageG<4096>(ws0 + O_W3R, WB[cur^1], w, lane);
    f32x4 au[2][2] = {{z,z},{z,z}};
    #pragma unroll
    for (int kc=0;kc<4;++kc){
      bf16x8 a0 = ld8(Hb +        l15*136 + kc*32 + quad*8);
      bf16x8 a1 = ld8(Hb + 2176 + l15*136 + kc*32 + quad*8);
      #pragma unroll
      for (int c=0;c<2;++c){
        bf16x8 bl = ldw(WB[cur], 128, c*16+l15, kc*4+quad);
        au[0][c] = MFMA16(a0, bl, au[0][c]);
        au[1][c] = MFMA16(a1, bl, au[1][c]);
      }
    }
    #pragma unroll
    for (int g=0;g<2;++g)
    #pragma unroll
    for (int c=0;c<2;++c)
      uf3[g][2+c] = shfrag(pkbf2(au[g][c][0],au[g][c][1]),
                           pkbf2(au[g][c][2],au[g][c][3]), laneA, laneB);
    __syncthreads(); cur ^= 1;
  }
  { // slot W3R h0; issue W3R h1
    stageG<4096>(ws0 + O_W3R + 4096, WB[cur^1], w, lane);
    #pragma unroll
    for (int g=0;g<2;++g){ av3[g][0]=z; av3[g][1]=z; }
    #pragma unroll
    for (int kc=0;kc<4;++kc){
      bf16x8 a0 = ld8(Hb +        l15*136 + kc*32 + quad*8);
      bf16x8 a1 = ld8(Hb + 2176 + l15*136 + kc*32 + quad*8);
      #pragma unroll
      for (int c=0;c<2;++c){
        bf16x8 br = ldw(WB[cur], 128, c*16+l15, kc*4+quad);
        av3[0][c] = MFMA16(a0, br, av3[0][c]);
        av3[1][c] = MFMA16(a1, br, av3[1][c]);
      }
    }
    #pragma unroll
    for (int g=0;g<2;++g)
    #pragma unroll
    for (int c=0;c<2;++c)
      av3[g][c] = MFMA16(aA[g], uf3[g][c], av3[g][c]);
    __syncthreads(); cur ^= 1;
  }
  { // slot W3R h1; issue T0 (full [64][64]); X written after all Hb reads
    stageG<4096>(ws0 + O_T0, WB[cur^1], w, lane);
    #pragma unroll
    for (int g=0;g<2;++g){ av3[g][2]=z; av3[g][3]=z; }
    #pragma unroll
    for (int kc=0;kc<4;++kc){
      bf16x8 a0 = ld8(Hb +        l15*136 + kc*32 + quad*8);
      bf16x8 a1 = ld8(Hb + 2176 + l15*136 + kc*32 + quad*8);
      #pragma unroll
      for (int c=0;c<2;++c){
        bf16x8 br = ldw(WB[cur], 128, c*16+l15, kc*4+quad);
        av3[0][2+c] = MFMA16(a0, br, av3[0][2+c]);
        av3[1][2+c] = MFMA16(a1, br, av3[1][2+c]);
      }
    }
    #pragma unroll
    for (int g=0;g<2;++g)
    #pragma unroll
    for (int c=0;c<2;++c)
      av3[g][2+c] = MFMA16(aA[g], uf3[g][2+c], av3[g][2+c]);
    #pragma unroll
    for (int c=0;c<4;++c){
      float bb = b3[c*16 + l15];
      #pragma unroll
      for (int g=0;g<2;++g)
      #pragma unroll
      for (int r=0;r<4;++r)
        X[g*1152 + (quad*4+r)*72 + c*16 + l15] = f2bf(av3[g][c][r] + bb);
    }
    FENCE();
    __syncthreads(); cur ^= 1;
  }

  // ---- TCN: 2 phases (T0 full: shift-operand; T1 full: x-operand) ----
  {
    f32x4 acct[2][4];
    #pragma unroll
    for (int g=0;g<2;++g)
    #pragma unroll
    for (int c=0;c<4;++c) acct[g][c]=z;
    { // slot T0; issue T1
      stageG<4096>(ws0 + O_T1, WB[cur^1], w, lane);
      #pragma unroll
      for (int kc=0;kc<2;++kc){
        bf16x8 as0 = (l15>0) ? ld8(X +        (l15-1)*72 + kc*32 + quad*8) : Z;
        bf16x8 as1 = (l15>0) ? ld8(X + 1152 + (l15-1)*72 + kc*32 + quad*8) : Z;
        #pragma unroll
        for (int c=0;c<4;++c){
          bf16x8 w0 = ldw(WB[cur], 64, c*16+l15, kc*4+quad);
          acct[0][c] = MFMA16(as0, w0, acct[0][c]);
          acct[1][c] = MFMA16(as1, w0, acct[1][c]);
        }
      }
      __syncthreads(); cur ^= 1;
    }
    { // slot T1; issue WQ; finish + store T + residual
      stageG<4096>(ws0 + O_WQ, WB[cur^1], w, lane);
      #pragma unroll
      for (int kc=0;kc<2;++kc){
        bf16x8 ax0 = ld8(X +        l15*72 + kc*32 + quad*8);
        bf16x8 ax1 = ld8(X + 1152 + l15*72 + kc*32 + quad*8);
        #pragma unroll
        for (int c=0;c<4;++c){
          bf16x8 w1 = ldw(WB[cur], 64, c*16+l15, kc*4+quad);
          acct[0][c] = MFMA16(ax0, w1, acct[0][c]);
          acct[1][c] = MFMA16(ax1, w1, acct[1][c]);
        }
      }
      #pragma unroll
      for (int c=0;c<4;++c){
        float tb = tcnb[c*16 + l15];
        #pragma unroll
        for (int g=0;g<2;++g)
        #pragma unroll
        for (int r=0;r<4;++r){
          float xr = bf2f(X[g*1152 + (quad*4+r)*72 + c*16 + l15]);
          T[g*1152 + (quad*4+r)*72 + c*16 + l15] =
              f2bf(fmaxf(acct[g][c][r]+tb, 0.f) + xr);
        }
      }
      FENCE();
      __syncthreads(); cur ^= 1;
    }
  }

  // ---- Q: 1 phase (WQ full); Qb over dead X; issue WK ----
  {
    stageG<4096>(ws0 + O_WK, WB[cur^1], w, lane);
    f32x4 aq[2][4];
    #pragma unroll
    for (int g=0;g<2;++g)
    #pragma unroll
    for (int c=0;c<4;++c) aq[g][c]=z;
    #pragma unroll
    for (int kc=0;kc<2;++kc){
      bf16x8 t0 = ld8(T +        l15*72 + kc*32 + quad*8);
      bf16x8 t1 = ld8(T + 1152 + l15*72 + kc*32 + quad*8);
      #pragma unroll
      for (int c=0;c<4;++c){
        bf16x8 b = ldw(WB[cur], 64, c*16+l15, kc*4+quad);
        aq[0][c] = MFMA16(t0, b, aq[0][c]);
        aq[1][c] = MFMA16(t1, b, aq[1][c]);
      }
    }
    #pragma unroll
    for (int c=0;c<4;++c)
    #pragma unroll
    for (int g=0;g<2;++g)
    #pragma unroll
    for (int r=0;r<4;++r)
      Qb[g*1152 + (quad*4+r)*72 + c*16 + l15] = f2bf(aq[g][c][r]);
    __syncthreads(); cur ^= 1;
  }

  // ---- K^T: 1 phase (WK as A-operand); issue WV; bK frags ----
  bf16x8 bK[2][4];
  {
    stageG<4096>(ws0 + O_WV, WB[cur^1], w, lane);
    f32x4 kt[2][4];
    #pragma unroll
    for (int g=0;g<2;++g)
    #pragma unroll
    for (int c=0;c<4;++c) kt[g][c]=z;
    #pragma unroll
    for (int kc=0;kc<2;++kc){
      bf16x8 t0 = ld8(T +        l15*72 + kc*32 + quad*8);
      bf16x8 t1 = ld8(T + 1152 + l15*72 + kc*32 + quad*8);
      #pragma unroll
      for (int c=0;c<4;++c){
        bf16x8 aW = ldw(WB[cur], 64, c*16+l15, kc*4+quad);
        kt[0][c] = MFMA16(aW, t0, kt[0][c]);
        kt[1][c] = MFMA16(aW, t1, kt[1][c]);
      }
    }
    #pragma unroll
    for (int g=0;g<2;++g)
    #pragma unroll
    for (int c=0;c<4;++c){
      bf16x8 f = shfrag(pkbf2(kt[g][c][0],kt[g][c][1]),
                        pkbf2(kt[g][c][2],kt[g][c][3]), laneA, laneB);
      bK[g][c] = (quad < 2) ? f : Z;     // K padded 16->32: zero upper half
    }
    __syncthreads(); cur ^= 1;
  }

  // ---- V: 1 phase (WV, last slot); bV frags ----
  bf16x8 bV[2][4];
  {
    f32x4 vv[2][4];
    #pragma unroll
    for (int g=0;g<2;++g)
    #pragma unroll
    for (int c=0;c<4;++c) vv[g][c]=z;
    #pragma unroll
    for (int kc=0;kc<2;++kc){
      bf16x8 t0 = ld8(T +        l15*72 + kc*32 + quad*8);
      bf16x8 t1 = ld8(T + 1152 + l15*72 + kc*32 + quad*8);
      #pragma unroll
      for (int c=0;c<4;++c){
        bf16x8 b = ldw(WB[cur], 64, c*16+l15, kc*4+quad);
        vv[0][c] = MFMA16(t0, b, vv[0][c]);
        vv[1][c] = MFMA16(t1, b, vv[1][c]);
      }
    }
    #pragma unroll
    for (int g=0;g<2;++g)
    #pragma unroll
    for (int c=0;c<4;++c)
      bV[g][c] = shfrag(pkbf2(vv[g][c][0],vv[g][c][1]),
                        pkbf2(vv[g][c][2],vv[g][c][3]), laneA, laneB);
  }
  FENCE();   // all T reads done; Pb (over T) safe to write

  // ---- S = (Q K^T)/4 per head; softmax across l15 lanes -> Pb ----
  #pragma unroll
  for (int g=0; g<2; ++g){
    unsigned short* Pbg = Pb + g*1024;
    #pragma unroll
    for (int h=0;h<4;++h){
      bf16x8 aQ = (quad < 2) ? ld8(Qb + g*1152 + l15*72 + h*16 + quad*8) : Z;
      f32x4 s4 = MFMA16(aQ, bK[g][h], z);
      #pragma unroll
      for (int r=0;r<4;++r){
        float s = s4[r]*0.25f;
        float m = s;
        m = fmaxf(m, __shfl_xor(m,1,64));
        m = fmaxf(m, __shfl_xor(m,2,64));
        m = fmaxf(m, __shfl_xor(m,4,64));
        m = fmaxf(m, __shfl_xor(m,8,64));
        float p = __expf(s-m);
        float su = p;
        su += __shfl_xor(su,1,64);
        su += __shfl_xor(su,2,64);
        su += __shfl_xor(su,4,64);
        su += __shfl_xor(su,8,64);
        Pbg[(h*16 + quad*4 + r)*16 + l15] = f2bf(p/su);
      }
    }
  }
  FENCE();

  // ---- O = P@V per head; column mean over 16 nodes in-register -> OM ----
  #pragma unroll
  for (int g=0; g<2; ++g){
    unsigned short* Pbg = Pb + g*1024;
    #pragma unroll
    for (int h=0;h<4;++h){
      bf16x8 aP = (quad < 2) ? ld8(Pbg + (h*16 + l15)*16 + quad*8) : Z;
      f32x4 o = MFMA16(aP, bV[g][h], z);
      float cs = o[0]+o[1]+o[2]+o[3];
      cs += __shfl_xor(cs, 16, 64);
      cs += __shfl_xor(cs, 32, 64);
      if (quad == 0) OMf[g*64 + h*16 + l15] = cs * (1.f/16.f);
    }
  }
  FENCE();

  // ---- feat = ((mean O) @ wo) @ wproj + bproj  (all fp32 scalar) ----
  {
    float t0 = 0.f, t1 = 0.f;
    #pragma unroll 8
    for (int d=0; d<64; ++d){
      float wv = wo[d*64 + lane];
      t0 += OMf[d]    * wv;
      t1 += OMf[64+d] * wv;
    }
    OMf[128+lane] = t0;
    OMf[192+lane] = t1;
    FENCE();
    float a00 = bproj[lane], a01 = bproj[lane+64];
    float a10 = a00, a11 = a01;
    #pragma unroll 8
    for (int m=0; m<64; ++m){
      float f0 = OMf[128+m], f1 = OMf[192+m];
      float w0 = wproj[m*128 + lane], w1 = wproj[m*128 + lane + 64];
      a00 += f0*w0; a01 += f0*w1;
      a10 += f1*w0; a11 += f1*w1;
    }
    feat[(size_t)gb0*128 + lane]        = f2bf(a00);
    feat[(size_t)gb0*128 + lane + 64]   = f2bf(a01);
    feat[(size_t)(gb0+1)*128 + lane]      = f2bf(a10);
    feat[(size_t)(gb0+1)*128 + lane + 64] = f2bf(a11);
  }
}

// ---------------------------------------------------------------------------
// per-variable fc heads: 1 wg = 1 kh; W1/W2 in padded LDS; pred written via
// LDS transpose as coalesced bursts; y-copy fused at tail. (r7-verified)
// ---------------------------------------------------------------------------
__global__ __launch_bounds__(256,4) void k_heads(
  const unsigned short* __restrict__ ws0,
  const float* __restrict__ fc1b, const float* __restrict__ fc2b,
  float* __restrict__ pred,
  const float4* __restrict__ ysrc, float4* __restrict__ ydst)
{
  __shared__ alignas(16) unsigned short W1s[64*136];
  __shared__ alignas(16) unsigned short W2s[32*72];
  __shared__ alignas(16) unsigned short hh[4*2304];
  const int tid=threadIdx.x, w=tid>>6, lane=tid&63, quad=lane>>4, l15=lane&15;
  const int kh = blockIdx.x >> 7;
  const int rb = (blockIdx.x & 127)*128 + w*32;   // this wave's 32 rows
  unsigned short* hw = hh + w*2304;
  const unsigned short* featg = ws0 + O_FEAT;
  const unsigned short* W1 = ws0 + O_FC1 + kh*8192;
  const unsigned short* W2 = ws0 + O_FC2 + kh*2048;

  #pragma unroll
  for (int it=0; it<4; ++it){
    int idx = it*2048 + tid*8;
    int row = idx >> 7, col = idx & 127;
    *(uint4*)(W1s + row*136 + col) = *(const uint4*)(W1 + idx);
  }
  {
    int idx = tid*8; int row = idx >> 6, col = idx & 63;
    *(uint4*)(W2s + row*72 + col) = *(const uint4*)(W2 + idx);
  }
  __syncthreads();

  f32x4 z = {0.f,0.f,0.f,0.f};
  f32x4 acc[2][4];
  #pragma unroll
  for (int t=0;t<2;++t)
  #pragma unroll
  for (int c=0;c<4;++c) acc[t][c]=z;
  #pragma unroll
  for (int kc=0;kc<4;++kc){
    bf16x8 a0 = ld8(featg + (size_t)(rb+l15)*128    + kc*32+quad*8);
    bf16x8 a1 = ld8(featg + (size_t)(rb+16+l15)*128 + kc*32+quad*8);
    #pragma unroll
    for (int c=0;c<4;++c){
      bf16x8 b = ld8(W1s + (c*16+l15)*136 + kc*32+quad*8);
      acc[0][c] = MFMA16(a0, b, acc[0][c]);
      acc[1][c] = MFMA16(a1, b, acc[1][c]);
    }
  }
  #pragma unroll
  for (int c=0;c<4;++c){
    float bb = fc1b[kh*64 + c*16+l15];
    #pragma unroll
    for (int t=0;t<2;++t)
    #pragma unroll
    for (int r=0;r<4;++r)
      hw[t*1152 + (quad*4+r)*72 + c*16+l15] = f2bf(fmaxf(acc[t][c][r]+bb, 0.f));
  }
  FENCE();
  f32x4 acc2[2][2];
  #pragma unroll
  for (int t=0;t<2;++t)
  #pragma unroll
  for (int c=0;c<2;++c) acc2[t][c]=z;
  #pragma unroll
  for (int kc=0;kc<2;++kc){
    bf16x8 a0 = ld8(hw +        l15*72 + kc*32+quad*8);
    bf16x8 a1 = ld8(hw + 1152 + l15*72 + kc*32+quad*8);
    #pragma unroll
    for (int c=0;c<2;++c){
      bf16x8 b = ld8(W2s + (c*16+l15)*72 + kc*32+quad*8);
      acc2[0][c] = MFMA16(a0, b, acc2[0][c]);
      acc2[1][c] = MFMA16(a1, b, acc2[1][c]);
    }
  }
  FENCE();   // all hw reads done; reuse hw as f32 staging for coalesced writes
  float* hf = (float*)hw;     // 1152 floats; we use 384 per tile
  #pragma unroll
  for (int t=0;t<2;++t){
    #pragma unroll
    for (int c=0;c<2;++c){
      int col = c*16+l15;
      if (col < 24){
        float bb = fc2b[kh*24+col];
        #pragma unroll
        for (int r=0;r<4;++r)
          hf[(quad*4+r)*24 + col] = acc2[t][c][r] + bb;
      }
    }
    FENCE();
    float* pb = pred + (size_t)kh*393216 + (size_t)(rb + t*16)*24;
    #pragma unroll
    for (int k=0;k<6;++k)
      pb[k*64 + lane] = hf[k*64 + lane];
    FENCE();
  }

  // fused yb copy: 2048 blocks x 256 threads x 3 = 1572864 float4 exact
  {
    int gidx = blockIdx.x*256 + tid;
    #pragma unroll
    for (int k=0;k<3;++k)
      ydst[gidx + k*524288] = ysrc[gidx + k*524288];
  }
}

// ---------------------------------------------------------------------------
extern "C" void kernel_launch(void* const* d_in, const int* in_sizes, int n_in,
                              void* d_out, int out_size, void* d_ws, size_t ws_size,
                              hipStream_t stream) {
  const float* x    = (const float*)d_in[0];
  const float* y    = (const float*)d_in[1];
  const int*   ei   = (const int*)d_in[2];
  const float* w1l  = (const float*)d_in[4];
  const float* w1r  = (const float*)d_in[5];
  const float* b1   = (const float*)d_in[6];
  const float* w2l  = (const float*)d_in[7];
  const float* w2r  = (const float*)d_in[8];
  const float* b2   = (const float*)d_in[9];
  const float* w3l  = (const float*)d_in[10];
  const float* w3r  = (const float*)d_in[11];
  const float* b3   = (const float*)d_in[12];
  const float* tcnw = (const float*)d_in[13];
  const float* tcnb = (const float*)d_in[14];
  const float* wq   = (const float*)d_in[15];
  const float* wk   = (const float*)d_in[16];
  const float* wv   = (const float*)d_in[17];
  const float* wo   = (const float*)d_in[18];
  const float* wpr  = (const float*)d_in[19];
  const float* bpr  = (const float*)d_in[20];
  const float* fc1w = (const float*)d_in[21];
  const float* fc1b = (const float*)d_in[22];
  const float* fc2w = (const float*)d_in[23];
  const float* fc2b = (const float*)d_in[24];

  unsigned short* W = (unsigned short*)d_ws;
  float* out = (float*)d_out;

  k_prep<<<1120, 256, 0, stream>>>(w1l,w1r,w2l,w2r,w3l,w3r,tcnw,wq,wk,wv,wo,fc1w,fc2w,W);
  k_fused<<<NGR/8, 256, 0, stream>>>(x, ei + EDGES, b1,b2,b3,tcnb, wo, wpr, bpr, W, W + O_FEAT);
  k_heads<<<2048, 256, 0, stream>>>(W, fc1b, fc2b, out,
                                    (const float4*)y, (float4*)(out + PRED_ELEMS));
}